// Round 9
// baseline (1196.135 us; speedup 1.0000x reference)
//
#include <hip/hip_runtime.h>
#include <cstdint>
#include <cstddef>

// HGT layer: N=100000, E=400000/rel, D=256, H=8, DK=32, R=2.
// Round 9: LDS-free, barrier-free split-bf16 MFMA GEMM.
//  - Each wave loads its own A rows (f32 -> in-register hi/lo bf16 split) and
//    B fragments directly from global (B = 1.5 MB, L2-resident). No __shared__,
//    no __syncthreads -> compiler pipelines loads under MFMA freely.
//  - m204 bijective XCD swizzle: consecutive logical blocks (sharing an A
//    M-tile) land on the same XCD -> A fetched ~once per XCD group.
//  - 3-term split: AhiBhi + AloBhi + AhiBlo (afh/bfh each loaded once, reused).
//  - Edge phase (merged CSR + dual-state online-softmax agg) unchanged.
//  - ws total 312.78 MB (proven good in round 8).

#define NN 100000
#define EE 400000

static constexpr float INV_SQRT_DK = 0.17677669529663687f; // 1/sqrt(32)

// ---------------- workspace layout (float offsets), total 78,194,496 f = 312.78 MB ----
static constexpr size_t OFF_Q      = 0;                                  // [N][256] f32
static constexpr size_t OFF_KV     = OFF_Q + (size_t)NN * 256;           // [N][1024] bf16
static constexpr size_t OFF_UNION  = OFF_KV + (size_t)NN * 512;
static constexpr size_t OFF_BBUF   = OFF_UNION;                          // [256][1280] f32 (dead after conv_B)
static constexpr size_t OFF_ROWPTR = OFF_UNION;                          // [N] int
static constexpr size_t OFF_CURSOR = OFF_ROWPTR + NN;                    // [N] int
static constexpr size_t OFF_SRCS   = OFF_CURSOR + NN;                    // [2E] int (PART aliases first 1024)
static constexpr size_t OFF_BIAS   = OFF_UNION + 1000000;                // [1280] f32
static constexpr size_t OFF_BT     = OFF_BIAS + 1280;                    // [1536][512] bf16
static constexpr size_t OFF_END    = OFF_BT + (size_t)1536 * 512 / 2;

using bf16x8 = __attribute__((ext_vector_type(8))) __bf16;
using f32x4v = __attribute__((ext_vector_type(4))) float;

static __device__ inline unsigned int bf_bits(__bf16 b) {
    union { __bf16 b; unsigned short u; } x; x.b = b; return (unsigned int)x.u;
}
static __device__ inline float bf2f(unsigned short u) {
    union { unsigned int u; float f; } x; x.u = ((unsigned int)u) << 16; return x.f;
}

// ---------------- zero fill ----------------
__global__ __launch_bounds__(256)
void zero_kernel(float4* __restrict__ p, long n4)
{
    const long stride = (long)gridDim.x * blockDim.x;
    for (long i = (long)blockIdx.x * blockDim.x + threadIdx.x; i < n4; i += stride)
        p[i] = make_float4(0.f, 0.f, 0.f, 0.f);
}

// ---------------- fused weight build (f32, into union BBUF) ----------------
__global__ __launch_bounds__(256)
void build_B_kernel(const float* __restrict__ Wk, const float* __restrict__ Wq,
                    const float* __restrict__ Wv,
                    const float* __restrict__ bk, const float* __restrict__ bq,
                    const float* __restrict__ bv,
                    const float* __restrict__ rel_att, const float* __restrict__ rel_msg,
                    float* __restrict__ Bbuf, float* __restrict__ biasbuf)
{
    const int din = blockIdx.x;   // 0..255 (input dim)
    const int t   = threadIdx.x;  // 0..255
    __shared__ float wk[256], wv[256];
    wk[t] = Wk[din * 256 + t];
    wv[t] = Wv[din * 256 + t];
    __syncthreads();
    const int h = t >> 5, e = t & 31;
    Bbuf[(size_t)din * 1280 + t] = Wq[din * 256 + t];
    #pragma unroll
    for (int r = 0; r < 2; ++r) {
        const float* ra = rel_att + (size_t)((r * 8 + h) * 32) * 32 + e;
        const float* rm = rel_msg + (size_t)((r * 8 + h) * 32) * 32 + e;
        float sa = 0.f, sm = 0.f;
        #pragma unroll
        for (int dd = 0; dd < 32; ++dd) {
            sa = fmaf(wk[h * 32 + dd], ra[dd * 32], sa);
            sm = fmaf(wv[h * 32 + dd], rm[dd * 32], sm);
        }
        Bbuf[(size_t)din * 1280 + 256 + r * 512 + t]       = sa;
        Bbuf[(size_t)din * 1280 + 256 + r * 512 + 256 + t] = sm;
    }
    if (din == 0) {
        biasbuf[t] = bq[t];
        #pragma unroll
        for (int r = 0; r < 2; ++r) {
            float sa = 0.f, sm = 0.f;
            #pragma unroll
            for (int dd = 0; dd < 32; ++dd) {
                sa = fmaf(bk[h * 32 + dd], rel_att[(size_t)((r * 8 + h) * 32 + dd) * 32 + e], sa);
                sm = fmaf(bv[h * 32 + dd], rel_msg[(size_t)((r * 8 + h) * 32 + dd) * 32 + e], sm);
            }
            biasbuf[256 + r * 512 + t]       = sa;
            biasbuf[256 + r * 512 + 256 + t] = sm;
        }
    }
}

// BBUF [256][1280] + Wa [256][256] -> BT [1536][512] bf16 (n-major; hi|lo)
__global__ __launch_bounds__(256)
void conv_B_kernel(const float* __restrict__ Bbuf, const float* __restrict__ Wa,
                   unsigned short* __restrict__ BT)
{
    const int n = blockIdx.x;    // 0..1535
    const int k = threadIdx.x;   // 0..255
    const float v = (n < 1280) ? Bbuf[(size_t)k * 1280 + n]
                               : Wa[(size_t)k * 256 + (n - 1280)];
    __bf16 hi = (__bf16)v;
    __bf16 lo = (__bf16)(v - (float)hi);
    BT[(size_t)n * 512 + k]       = (unsigned short)bf_bits(hi);
    BT[(size_t)n * 512 + 256 + k] = (unsigned short)bf_bits(lo);
}

// ---------------- LDS-free split-bf16 MFMA GEMM ----------------
// C = alpha*(A_f32 @ B) + bias. BT [Nc][512] bf16 n-major (hi k0..255 | lo).
// 128x128 tile, 4 waves (2x2), per-wave 64x64 via 4x4 16x16x32 frags.
// All operands loaded per-wave directly from global; no LDS, no barriers.
__global__ __launch_bounds__(256, 2)
void gemm_mfma(const float* __restrict__ A, int lda,
               const unsigned short* __restrict__ BT,
               const float* __restrict__ bias,
               float* __restrict__ Qout, unsigned short* __restrict__ KVout,
               int M, int nbn, float alpha)
{
    // m204 bijective XCD swizzle: contiguous logical ids per XCD
    const int nwg = gridDim.x;
    const int q = nwg >> 3, r = nwg & 7;
    const int xcd = blockIdx.x & 7, idx = blockIdx.x >> 3;
    const int logical = (xcd < r ? xcd * (q + 1) : r * (q + 1) + (xcd - r) * q) + idx;
    const int bn = (logical % nbn) * 128;
    const int bm = (logical / nbn) * 128;

    const int tid = threadIdx.x;
    const int wid = tid >> 6;
    const int l   = tid & 63;
    const int wm  = (wid >> 1) * 64;
    const int wn  = (wid & 1) * 64;
    const int l15 = l & 15;
    const int k8  = (l >> 4) * 8;   // f32-k offset (0,8,16,24)

    f32x4v acc[4][4];
    #pragma unroll
    for (int i = 0; i < 4; ++i)
        #pragma unroll
        for (int j = 0; j < 4; ++j)
            acc[i][j] = (f32x4v){0.f, 0.f, 0.f, 0.f};

    // per-lane base pointers (A row clamped in-bounds; value zeroed via aok)
    const float* Abase[4];
    bool aok[4];
    #pragma unroll
    for (int i = 0; i < 4; ++i) {
        const int grow = bm + wm + i * 16 + l15;
        aok[i] = grow < M;
        Abase[i] = A + (size_t)(aok[i] ? grow : 0) * lda + k8;
    }
    const unsigned short* Bbase[4];
    #pragma unroll
    for (int j = 0; j < 4; ++j)
        Bbase[j] = BT + (size_t)(bn + wn + j * 16 + l15) * 512 + k8;

    const float4 fz = make_float4(0.f, 0.f, 0.f, 0.f);
    float4 ra0[4], ra1[4];
    #pragma unroll
    for (int i = 0; i < 4; ++i) {
        float4 t0 = *reinterpret_cast<const float4*>(Abase[i]);
        float4 t1 = *reinterpret_cast<const float4*>(Abase[i] + 4);
        ra0[i] = aok[i] ? t0 : fz;
        ra1[i] = aok[i] ? t1 : fz;
    }

    for (int kb = 0; kb < 8; ++kb) {
        // B fragments for this step (L2-hot; issued early)
        bf16x8 bfh[4], bfl[4];
        #pragma unroll
        for (int j = 0; j < 4; ++j)
            bfh[j] = *reinterpret_cast<const bf16x8*>(Bbase[j] + kb * 32);
        #pragma unroll
        for (int j = 0; j < 4; ++j)
            bfl[j] = *reinterpret_cast<const bf16x8*>(Bbase[j] + 256 + kb * 32);
        // convert rawA(kb) -> hi/lo fragments
        bf16x8 afh[4], afl[4];
        #pragma unroll
        for (int i = 0; i < 4; ++i) {
            const float v[8] = {ra0[i].x, ra0[i].y, ra0[i].z, ra0[i].w,
                                ra1[i].x, ra1[i].y, ra1[i].z, ra1[i].w};
            bf16x8 hh, ll;
            #pragma unroll
            for (int e = 0; e < 8; ++e) {
                const __bf16 hb = (__bf16)v[e];
                hh[e] = hb;
                ll[e] = (__bf16)(v[e] - (float)hb);
            }
            afh[i] = hh;
            afl[i] = ll;
        }
        // prefetch rawA(kb+1) under the MFMAs
        if (kb < 7) {
            #pragma unroll
            for (int i = 0; i < 4; ++i) {
                float4 t0 = *reinterpret_cast<const float4*>(Abase[i] + (kb + 1) * 32);
                float4 t1 = *reinterpret_cast<const float4*>(Abase[i] + (kb + 1) * 32 + 4);
                ra0[i] = aok[i] ? t0 : fz;
                ra1[i] = aok[i] ? t1 : fz;
            }
        }
        // term0: Ahi x Bhi
        #pragma unroll
        for (int i = 0; i < 4; ++i)
            #pragma unroll
            for (int j = 0; j < 4; ++j)
                acc[i][j] = __builtin_amdgcn_mfma_f32_16x16x32_bf16(afh[i], bfh[j], acc[i][j], 0, 0, 0);
        // term1: Alo x Bhi
        #pragma unroll
        for (int i = 0; i < 4; ++i)
            #pragma unroll
            for (int j = 0; j < 4; ++j)
                acc[i][j] = __builtin_amdgcn_mfma_f32_16x16x32_bf16(afl[i], bfh[j], acc[i][j], 0, 0, 0);
        // term2: Ahi x Blo
        #pragma unroll
        for (int i = 0; i < 4; ++i)
            #pragma unroll
            for (int j = 0; j < 4; ++j)
                acc[i][j] = __builtin_amdgcn_mfma_f32_16x16x32_bf16(afh[i], bfl[j], acc[i][j], 0, 0, 0);
    }

    // epilogue: C/D layout col=lane&15, row=(lane>>4)*4+reg (m89-verified)
    const bool q_seg = (bn < 256);
    #pragma unroll
    for (int i = 0; i < 4; ++i) {
        const int rbase = bm + wm + i * 16 + (l >> 4) * 4;
        #pragma unroll
        for (int j = 0; j < 4; ++j) {
            const int col = bn + wn + j * 16 + l15;
            const float bcol = bias[col];
            #pragma unroll
            for (int rr = 0; rr < 4; ++rr) {
                const int row = rbase + rr;
                if (row < M) {
                    const float o = alpha * acc[i][j][rr] + bcol;
                    if (q_seg)
                        Qout[(size_t)row * 256 + col] = o;
                    else
                        KVout[(size_t)row * 1024 + (col - 256)] = (unsigned short)bf_bits((__bf16)o);
                }
            }
        }
    }
}

// ---------------- combined CSR build (both relations) ----------------
__global__ __launch_bounds__(256)
void hist2_kernel(const int* __restrict__ dst0, const int* __restrict__ dst1,
                  int* __restrict__ deg)
{
    const int stride = gridDim.x * blockDim.x;
    for (int i = blockIdx.x * blockDim.x + threadIdx.x; i < 2 * EE; i += stride) {
        const int d = (i < EE) ? dst0[i] : dst1[i - EE];
        atomicAdd(&deg[d], 1);
    }
}

__global__ __launch_bounds__(1024)
void scan1_kernel(const int* __restrict__ deg, int* __restrict__ rowptr,
                  int* __restrict__ part, int n)
{
    __shared__ int sm[1024];
    const int tid = threadIdx.x;
    const int i = blockIdx.x * 1024 + tid;
    const int v = (i < n) ? deg[i] : 0;
    sm[tid] = v;
    __syncthreads();
    for (int off = 1; off < 1024; off <<= 1) {
        int add = (tid >= off) ? sm[tid - off] : 0;
        __syncthreads();
        sm[tid] += add;
        __syncthreads();
    }
    if (i < n) rowptr[i] = sm[tid] - v;
    if (tid == 1023) part[blockIdx.x] = sm[1023];
}

__global__ __launch_bounds__(1024)
void scan2_kernel(int* __restrict__ part, int np)
{
    __shared__ int sm[1024];
    const int tid = threadIdx.x;
    const int v = (tid < np) ? part[tid] : 0;
    sm[tid] = v;
    __syncthreads();
    for (int off = 1; off < 1024; off <<= 1) {
        int add = (tid >= off) ? sm[tid - off] : 0;
        __syncthreads();
        sm[tid] += add;
        __syncthreads();
    }
    if (tid < np) part[tid] = sm[tid] - v;
}

__global__ __launch_bounds__(256)
void scan3_kernel(int* __restrict__ rowptr, int* __restrict__ cursor,
                  const int* __restrict__ part, int n)
{
    const int i = blockIdx.x * 256 + threadIdx.x;
    if (i < n) {
        const int r = rowptr[i] + part[i >> 10];
        rowptr[i] = r;
        cursor[i] = r;
    }
}

// scatter both relations; srcs entry = src | (rel << 20)
__global__ __launch_bounds__(256)
void scatter2_kernel(const int* __restrict__ src0, const int* __restrict__ dst0,
                     const int* __restrict__ src1, const int* __restrict__ dst1,
                     int* __restrict__ cursor, int* __restrict__ srcs)
{
    const int stride = gridDim.x * blockDim.x;
    for (int i = blockIdx.x * blockDim.x + threadIdx.x; i < 2 * EE; i += stride) {
        const int rel = (i >= EE);
        const int e = rel ? (i - EE) : i;
        const int d  = rel ? dst1[e] : dst0[e];
        const int sv = (rel ? src1[e] : src0[e]) | (rel << 20);
        int pos = atomicAdd(&cursor[d], 1);
        srcs[pos] = sv;
    }
}

// ---------------- merged dual-relation online-softmax aggregation ----------------
__global__ __launch_bounds__(256)
void node_agg2_kernel(const float* __restrict__ Q, const unsigned short* __restrict__ KV,
                      const int* __restrict__ rowptr, const int* __restrict__ endptr,
                      const int* __restrict__ srcs,
                      const float* __restrict__ rel_pri,  // [16]
                      float* __restrict__ AGG)
{
    const int node = (blockIdx.x * blockDim.x + threadIdx.x) >> 6;
    if (node >= NN) return;
    const int l = threadIdx.x & 63;
    const int h = l >> 3;
    const float4 q4 = reinterpret_cast<const float4*>(Q + (size_t)node * 256)[l];
    const float pr0 = rel_pri[h] * INV_SQRT_DK;
    const float pr1 = rel_pri[8 + h] * INV_SQRT_DK;
    const int s0 = rowptr[node];
    const int s1 = endptr[node];
    float m0 = -3.0e38f, m1 = -3.0e38f, den0 = 0.f, den1 = 0.f;
    float4 a0 = make_float4(0.f, 0.f, 0.f, 0.f);
    float4 a1 = make_float4(0.f, 0.f, 0.f, 0.f);
    #pragma unroll 2
    for (int i = s0; i < s1; ++i) {
        const int p = srcs[i];
        const int s = p & 0xFFFFF;
        const int rel = p >> 20;
        const unsigned short* kv = KV + (size_t)s * 1024 + (rel << 9);
        const ushort4 k4 = *reinterpret_cast<const ushort4*>(kv + l * 4);
        float t = q4.x * bf2f(k4.x) + q4.y * bf2f(k4.y) + q4.z * bf2f(k4.z) + q4.w * bf2f(k4.w);
        t += __shfl_xor(t, 1, 64);
        t += __shfl_xor(t, 2, 64);
        t += __shfl_xor(t, 4, 64);
        const ushort4 v4 = *reinterpret_cast<const ushort4*>(kv + 256 + l * 4);
        const float vx = bf2f(v4.x), vy = bf2f(v4.y), vz = bf2f(v4.z), vw = bf2f(v4.w);
        if (rel == 0) {
            const float sc = t * pr0;
            const float mn = fmaxf(m0, sc);
            const float scale = __expf(m0 - mn);
            const float ex = __expf(sc - mn);
            den0 = den0 * scale + ex;
            a0.x = a0.x * scale + vx * ex;
            a0.y = a0.y * scale + vy * ex;
            a0.z = a0.z * scale + vz * ex;
            a0.w = a0.w * scale + vw * ex;
            m0 = mn;
        } else {
            const float sc = t * pr1;
            const float mn = fmaxf(m1, sc);
            const float scale = __expf(m1 - mn);
            const float ex = __expf(sc - mn);
            den1 = den1 * scale + ex;
            a1.x = a1.x * scale + vx * ex;
            a1.y = a1.y * scale + vy * ex;
            a1.z = a1.z * scale + vz * ex;
            a1.w = a1.w * scale + vw * ex;
            m1 = mn;
        }
    }
    const float i0 = (den0 > 0.f) ? 1.0f / den0 : 0.f;
    const float i1 = (den1 > 0.f) ? 1.0f / den1 : 0.f;
    float4 o;
    o.x = a0.x * i0 + a1.x * i1;
    o.y = a0.y * i0 + a1.y * i1;
    o.z = a0.z * i0 + a1.z * i1;
    o.w = a0.w * i0 + a1.w * i1;
    reinterpret_cast<float4*>(AGG + (size_t)node * 256)[l] = o;
}

// ---------------- residual + LayerNorm ----------------
__global__ __launch_bounds__(256)
void ln_kernel(const float* __restrict__ tmp, const float* __restrict__ hres,
               const float* __restrict__ g, const float* __restrict__ b,
               float* __restrict__ out, int M)
{
    const int gtid = blockIdx.x * blockDim.x + threadIdx.x;
    const int wid = gtid >> 6;
    const int nw = (gridDim.x * blockDim.x) >> 6;
    const int lane = threadIdx.x & 63;
    const float4 gv = reinterpret_cast<const float4*>(g)[lane];
    const float4 bv = reinterpret_cast<const float4*>(b)[lane];
    for (int row = wid; row < M; row += nw) {
        const float4 tv = reinterpret_cast<const float4*>(tmp + (size_t)row * 256)[lane];
        const float4 hv = reinterpret_cast<const float4*>(hres + (size_t)row * 256)[lane];
        float y0 = tv.x + hv.x, y1 = tv.y + hv.y, y2 = tv.z + hv.z, y3 = tv.w + hv.w;
        float ssum = y0 + y1 + y2 + y3;
        #pragma unroll
        for (int off = 32; off; off >>= 1) ssum += __shfl_xor(ssum, off, 64);
        const float mean = ssum * (1.f / 256.f);
        const float d0 = y0 - mean, d1 = y1 - mean, d2 = y2 - mean, d3 = y3 - mean;
        float sq = d0 * d0 + d1 * d1 + d2 * d2 + d3 * d3;
        #pragma unroll
        for (int off = 32; off; off >>= 1) sq += __shfl_xor(sq, off, 64);
        const float inv = rsqrtf(sq * (1.f / 256.f) + 1e-5f);
        float4 o;
        o.x = d0 * inv * gv.x + bv.x;
        o.y = d1 * inv * gv.y + bv.y;
        o.z = d2 * inv * gv.z + bv.z;
        o.w = d3 * inv * gv.w + bv.w;
        reinterpret_cast<float4*>(out + (size_t)row * 256)[lane] = o;
    }
}

extern "C" void kernel_launch(void* const* d_in, const int* in_sizes, int n_in,
                              void* d_out, int out_size, void* d_ws, size_t ws_size,
                              hipStream_t stream)
{
    const float* h    = (const float*)d_in[0];
    const int* src0   = (const int*)d_in[1];
    const int* dst0   = (const int*)d_in[2];
    const int* src1   = (const int*)d_in[3];
    const int* dst1   = (const int*)d_in[4];
    const float* Wk   = (const float*)d_in[5];
    const float* bk   = (const float*)d_in[6];
    const float* Wq   = (const float*)d_in[7];
    const float* bq   = (const float*)d_in[8];
    const float* Wv   = (const float*)d_in[9];
    const float* bv   = (const float*)d_in[10];
    const float* Wa   = (const float*)d_in[11];
    const float* ba   = (const float*)d_in[12];
    const float* lng  = (const float*)d_in[13];
    const float* lnb  = (const float*)d_in[14];
    const float* rel_pri = (const float*)d_in[15];
    const float* rel_att = (const float*)d_in[16];
    const float* rel_msg = (const float*)d_in[17];

    float* ws    = (float*)d_ws;
    float* Q     = ws + OFF_Q;
    unsigned short* KV = (unsigned short*)(ws + OFF_KV);
    float* BBUF  = ws + OFF_BBUF;
    float* BIAS  = ws + OFF_BIAS;
    int* ROWPTR  = (int*)(ws + OFF_ROWPTR);
    int* CURSOR  = (int*)(ws + OFF_CURSOR);
    int* SRCS    = (int*)(ws + OFF_SRCS);
    int* PART    = SRCS;              // first 1024 ints; dead before scatter writes
    unsigned short* BT = (unsigned short*)(ws + OFF_BT);
    float* AGG   = (float*)d_out;     // scratch until final LN
    float* TMP   = ws + OFF_Q;        // GEMM3 output aliases dead Q

    const int NSCAN = (NN + 1023) / 1024;   // 98

    // fused weights -> BBUF/BIAS, then bf16 split-transpose -> BT (BBUF dies)
    build_B_kernel<<<256, 256, 0, stream>>>(Wk, Wq, Wv, bk, bq, bv,
                                            rel_att, rel_msg, BBUF, BIAS);
    conv_B_kernel<<<1536, 256, 0, stream>>>(BBUF, Wa, BT);

    // fused projection: [N,256] x [256,1280] -> q f32 | kr0,vr0,kr1,vr1 bf16
    {
        const int nwg = 10 * ((NN + 127) / 128);   // 7820
        gemm_mfma<<<nwg, 256, 0, stream>>>(h, 256, BT, BIAS, Q, KV, NN, 10, 1.0f);
    }

    // combined CSR over both relations
    zero_kernel<<<128, 256, 0, stream>>>((float4*)CURSOR, (long)NN / 4);
    hist2_kernel<<<1024, 256, 0, stream>>>(dst0, dst1, CURSOR);
    scan1_kernel<<<NSCAN, 1024, 0, stream>>>(CURSOR, ROWPTR, PART, NN);
    scan2_kernel<<<1, 1024, 0, stream>>>(PART, NSCAN);
    scan3_kernel<<<(NN + 255) / 256, 256, 0, stream>>>(ROWPTR, CURSOR, PART, NN);
    scatter2_kernel<<<1024, 256, 0, stream>>>(src0, dst0, src1, dst1, CURSOR, SRCS);

    // merged aggregation (single AGG write)
    node_agg2_kernel<<<NN * 64 / 256, 256, 0, stream>>>(Q, KV, ROWPTR, CURSOR, SRCS,
                                                        rel_pri, AGG);

    // GEMM3: tmp = 0.5*(agg @ Wa) + ba  (bn<256 -> f32 Qout path)
    {
        const int nwg = 2 * ((NN + 127) / 128);    // 1564
        gemm_mfma<<<nwg, 256, 0, stream>>>(AGG, 256, BT + (size_t)1280 * 512, ba,
                                           TMP, KV, NN, 2, 0.5f);
    }
    // residual + layernorm
    ln_kernel<<<2048, 256, 0, stream>>>(TMP, h, lng, lnb, (float*)d_out, NN);
}